// Round 8
// baseline (337.655 us; speedup 1.0000x reference)
//
#include <hip/hip_runtime.h>
#include <math.h>

// MMD loss, single-pass fp16 MFMA. N=M=4096, D=1024, sigma^2=2025.
// x -> xh = fp16(x) (RNE); norms computed FROM THE ROUNDED vectors so the
// kernel evaluates the exact MMD of the perturbed sets {xh},{yh}. Per-block
// fp64 partials + tiny reduce kernel (NO fences in main kernel: round-4
// showed agent-scope fence = per-XCD L2 invalidate, 1.45x slowdown).
// Round 8: BARRIER-FREE K-loop. Rounds 5-7 showed every LDS variant
// (2-barrier, dbuf, swizzle, BK=32/64) pinned at 98-120 us: the per-step
// s_waitcnt vmcnt(0)+s_barrier drain with ~2 blocks/CU TLP is the wall.
// The 16x16x32 frag layout (row=lane&15, 16 B at k=quad*8) is directly
// loadable from row-major global: 16 rows x 64 B = 16 full lines per
// instr (same as coalesced dwordx4). Each wave loads its own frags to
// VGPRs — no LDS, no __syncthreads in the loop — so loads pipeline across
// MFMAs freely; wave pairs reading identical frags dedup in L1.

typedef _Float16 f16_t;
typedef _Float16 f16x4 __attribute__((ext_vector_type(4)));
typedef _Float16 f16x8 __attribute__((ext_vector_type(8)));
typedef float floatx4 __attribute__((ext_vector_type(4)));

#define NROWS 4096
#define MROWS 4096
#define DDIM  1024
#define BM    128
#define NT    (NROWS / BM)            // 32 tiles per dim
#define TRI   (NT * (NT + 1) / 2)     // 528 triangular tiles
#define NBLK  (2 * TRI + NT * NT)     // 2080 blocks

// ---------------------------------------------------------------- convert
// Wave-per-row: 2048 blocks x 4 waves cover 8192 rows. Each lane loads
// 4 float4 (64 lanes x 16 B = 1 KB per instr, fully coalesced), converts to
// fp16, stores f16x4; norm of the ROUNDED row shuffle-reduced in-wave.
__global__ __launch_bounds__(256) void convert_kernel(
    const float* __restrict__ X, const float* __restrict__ Y,
    f16_t* __restrict__ Xh, f16_t* __restrict__ Yh,
    float* __restrict__ nx, float* __restrict__ ny) {
    const int wid  = threadIdx.x >> 6;
    const int lane = threadIdx.x & 63;
    const int row  = blockIdx.x * 4 + wid;        // 0..8191
    const float* src;
    f16_t* dst;
    float* nrm;
    int r;
    if (row < NROWS) {
        r = row;         src = X + (size_t)r * DDIM;
        dst = Xh + (size_t)r * DDIM;  nrm = nx;
    } else {
        r = row - NROWS; src = Y + (size_t)r * DDIM;
        dst = Yh + (size_t)r * DDIM;  nrm = ny;
    }
    const float4* s4 = (const float4*)src;        // 256 float4 per row
    f16x4* d4 = (f16x4*)dst;
    float s = 0.f;
    #pragma unroll
    for (int c = 0; c < 4; c++) {
        float4 v = s4[c * 64 + lane];
        f16x4 h;
        h[0] = (f16_t)v.x; h[1] = (f16_t)v.y;
        h[2] = (f16_t)v.z; h[3] = (f16_t)v.w;
        d4[c * 64 + lane] = h;
        float h0 = (float)h[0], h1 = (float)h[1];
        float h2 = (float)h[2], h3 = (float)h[3];
        s += h0 * h0 + h1 * h1 + h2 * h2 + h3 * h3;
    }
    #pragma unroll
    for (int off = 32; off > 0; off >>= 1) s += __shfl_down(s, off);
    if (lane == 0) nrm[r] = s;
}

// ---------------------------------------------------------------- main GEMM
__global__ __launch_bounds__(256, 3) void mmd_mfma(
    const f16_t* __restrict__ Xh, const f16_t* __restrict__ Yh,
    const float* __restrict__ nx, const float* __restrict__ ny,
    double* __restrict__ partials) {
    __shared__ double wred[4];

    const int b = blockIdx.x;
    const f16_t *A, *B;
    const float *nA, *nB;
    int tr, tc;
    double coef;
    if (b < 2 * TRI) {
        int u = (b < TRI) ? b : b - TRI;
        int r = 0;
        while (u >= NT - r) { u -= NT - r; r++; }
        tr = r; tc = r + u;
        double w = (tr == tc) ? 1.0 : 2.0;   // off-diagonal tiles count twice
        if (b < TRI) { A = Xh; B = Xh; nA = nx; nB = nx;
                       coef = w / ((double)NROWS * (double)(NROWS - 1)); }
        else         { A = Yh; B = Yh; nA = ny; nB = ny;
                       coef = w / ((double)MROWS * (double)(MROWS - 1)); }
    } else {
        int u = b - 2 * TRI;
        tr = u / NT; tc = u % NT;
        A = Xh; B = Yh; nA = nx; nB = ny;
        coef = -2.0 / ((double)NROWS * (double)MROWS);
    }

    const int t    = threadIdx.x;
    const int wave = t >> 6;            // 0..3; waves 2x2: wm=wave>>1, wn=wave&1
    const int lane = t & 63;
    const int wm   = wave >> 1;
    const int wn   = wave & 1;
    const int m    = lane & 15;         // frag row within 16x16 subtile
    const int quad = lane >> 4;         // k-chunk: k = quad*8 + j

    // per-subtile fragment base pointers (A-layout == B-layout: row, k-chunk)
    const f16_t* arow[4];
    const f16_t* brow[4];
    #pragma unroll
    for (int s = 0; s < 4; s++) {
        arow[s] = A + (size_t)(tr * BM + wm * 64 + s * 16 + m) * DDIM + quad * 8;
        brow[s] = B + (size_t)(tc * BM + wn * 64 + s * 16 + m) * DDIM + quad * 8;
    }

    floatx4 acc[4][4];
    #pragma unroll
    for (int i = 0; i < 4; i++)
        #pragma unroll
        for (int j = 0; j < 4; j++) acc[i][j] = (floatx4){0.f, 0.f, 0.f, 0.f};

    // 2-stage register rotation, 64 k per outer iter, no barriers anywhere
    f16x8 a0[4], b0[4], a1[4], b1[4];
    #pragma unroll
    for (int s = 0; s < 4; s++) {
        a0[s] = *(const f16x8*)(arow[s]);
        b0[s] = *(const f16x8*)(brow[s]);
    }
    for (int k0 = 0; k0 < DDIM; k0 += 64) {
        #pragma unroll
        for (int s = 0; s < 4; s++) {
            a1[s] = *(const f16x8*)(arow[s] + k0 + 32);
            b1[s] = *(const f16x8*)(brow[s] + k0 + 32);
        }
        #pragma unroll
        for (int i = 0; i < 4; i++)
            #pragma unroll
            for (int j = 0; j < 4; j++)
                acc[i][j] = __builtin_amdgcn_mfma_f32_16x16x32_f16(a0[i], b0[j], acc[i][j], 0, 0, 0);
        if (k0 + 64 < DDIM) {
            #pragma unroll
            for (int s = 0; s < 4; s++) {
                a0[s] = *(const f16x8*)(arow[s] + k0 + 64);
                b0[s] = *(const f16x8*)(brow[s] + k0 + 64);
            }
        }
        #pragma unroll
        for (int i = 0; i < 4; i++)
            #pragma unroll
            for (int j = 0; j < 4; j++)
                acc[i][j] = __builtin_amdgcn_mfma_f32_16x16x32_f16(a1[i], b1[j], acc[i][j], 0, 0, 0);
    }

    // epilogue: C/D layout col=lane&15 (B-row), row=quad*4+reg (A-row)
    float na[16], nb[4];
    #pragma unroll
    for (int i = 0; i < 4; i++) {
        #pragma unroll
        for (int r = 0; r < 4; r++)
            na[i * 4 + r] = nA[tr * BM + wm * 64 + i * 16 + quad * 4 + r];
        nb[i] = nB[tc * BM + wn * 64 + i * 16 + m];
    }
    const float inv_s2 = 1.0f / 2025.0f;
    float lsum = 0.f;
    #pragma unroll
    for (int i = 0; i < 4; i++)
        #pragma unroll
        for (int j = 0; j < 4; j++)
            #pragma unroll
            for (int r = 0; r < 4; r++) {
                float arg = (2.f * acc[i][j][r] - na[i * 4 + r] - nb[j]) * inv_s2;
                lsum += __expf(arg);
            }

    // in-wave fp64 reduce (no barriers), then 4-wave LDS combine; plain store
    double d = (double)lsum;
    #pragma unroll
    for (int off = 32; off > 0; off >>= 1) d += __shfl_down(d, off);
    if (lane == 0) wred[wave] = d;
    __syncthreads();
    if (t == 0)
        partials[b] = (wred[0] + wred[1] + wred[2] + wred[3]) * coef;
}

__global__ __launch_bounds__(256) void final_reduce(const double* __restrict__ partials,
                                                    float* __restrict__ out) {
    __shared__ double red[256];
    int t = threadIdx.x;
    double s = 0.0;
    for (int i = t; i < NBLK; i += 256) s += partials[i];
    red[t] = s;
    __syncthreads();
    for (int off = 128; off > 0; off >>= 1) {
        if (t < off) red[t] += red[t + off];
        __syncthreads();
    }
    if (t == 0) {
        // analytic diagonal subtraction: 1/(n-1) + 1/(m-1)
        double mmd = red[0] - 1.0 / (double)(NROWS - 1) - 1.0 / (double)(MROWS - 1);
        out[0] = (float)mmd;
    }
}

extern "C" void kernel_launch(void* const* d_in, const int* in_sizes, int n_in,
                              void* d_out, int out_size, void* d_ws, size_t ws_size,
                              hipStream_t stream) {
    const float* X = (const float*)d_in[0];   // inputs  [4096,1024] fp32
    const float* Y = (const float*)d_in[1];   // samples [4096,1024] fp32
    float* out = (float*)d_out;

    // workspace: partials | nx | ny | Xh | Yh  (~16.7 MB)
    char* p = (char*)d_ws;
    double* partials = (double*)p;            p += ((size_t)NBLK * sizeof(double) + 255) & ~255ULL;
    float* nx = (float*)p;                    p += (size_t)NROWS * sizeof(float);
    float* ny = (float*)p;                    p += (size_t)MROWS * sizeof(float);
    f16_t* Xh = (f16_t*)p;                    p += (size_t)NROWS * DDIM * sizeof(f16_t);
    f16_t* Yh = (f16_t*)p;

    convert_kernel<<<(NROWS + MROWS) / 4, 256, 0, stream>>>(X, Y, Xh, Yh, nx, ny);
    mmd_mfma<<<NBLK, 256, 0, stream>>>(Xh, Yh, nx, ny, partials);
    final_reduce<<<1, 256, 0, stream>>>(partials, out);
}

// Round 9
// 195.278 us; speedup vs baseline: 1.7291x; 1.7291x over previous
//
#include <hip/hip_runtime.h>
#include <math.h>

// MMD loss, single-pass fp16 MFMA. N=M=4096, D=1024, sigma^2=2025.
// x -> xh = fp16(x) (RNE); norms computed FROM THE ROUNDED vectors so the
// kernel evaluates the exact MMD of the perturbed sets {xh},{yh}. Per-block
// fp64 partials + tiny reduce kernel (NO fences in main kernel: round-4
// showed agent-scope fence = per-XCD L2 invalidate, 1.45x slowdown).
// Round 9: 256x256 tiles. Rounds 2/3/5/6/7 all pin logical-bytes-through-L2
// at ~9-10.5 TB/s regardless of barrier count / conflicts / dbuf -> the
// kernel is L2/L3 delivery-BW bound, not latency/drain bound (round-8's
// VGPR-direct experiment also confirmed LDS sharing is essential). Doubling
// tile size halves staged traffic: 528 blocks x 1 MB = 528 MB (was 1.04 GB).
// 512 threads, 8 waves in 4x2; each wave 64x128 (4x8 frags). Two-barrier
// single-buffer K-loop kept (proven best of all variants).

typedef _Float16 f16_t;
typedef _Float16 f16x4 __attribute__((ext_vector_type(4)));
typedef _Float16 f16x8 __attribute__((ext_vector_type(8)));
typedef float floatx4 __attribute__((ext_vector_type(4)));

#define NROWS 4096
#define MROWS 4096
#define DDIM  1024
#define BM    256
#define BK    32                      // fp16 elements per K-step (64 B/row)
#define TILE  (BM * BK)               // 8192 f16 per tile (16 KB)
#define NT    (NROWS / BM)            // 16 tiles per dim
#define TRI   (NT * (NT + 1) / 2)     // 136 triangular tiles
#define NBLK  (2 * TRI + NT * NT)     // 136+136+256 = 528 blocks

// ---------------------------------------------------------------- convert
// Wave-per-row: 2048 blocks x 4 waves cover 8192 rows. Each lane loads
// 4 float4 (64 lanes x 16 B = 1 KB per instr, fully coalesced), converts to
// fp16, stores f16x4; norm of the ROUNDED row shuffle-reduced in-wave.
__global__ __launch_bounds__(256) void convert_kernel(
    const float* __restrict__ X, const float* __restrict__ Y,
    f16_t* __restrict__ Xh, f16_t* __restrict__ Yh,
    float* __restrict__ nx, float* __restrict__ ny) {
    const int wid  = threadIdx.x >> 6;
    const int lane = threadIdx.x & 63;
    const int row  = blockIdx.x * 4 + wid;        // 0..8191
    const float* src;
    f16_t* dst;
    float* nrm;
    int r;
    if (row < NROWS) {
        r = row;         src = X + (size_t)r * DDIM;
        dst = Xh + (size_t)r * DDIM;  nrm = nx;
    } else {
        r = row - NROWS; src = Y + (size_t)r * DDIM;
        dst = Yh + (size_t)r * DDIM;  nrm = ny;
    }
    const float4* s4 = (const float4*)src;        // 256 float4 per row
    f16x4* d4 = (f16x4*)dst;
    float s = 0.f;
    #pragma unroll
    for (int c = 0; c < 4; c++) {
        float4 v = s4[c * 64 + lane];
        f16x4 h;
        h[0] = (f16_t)v.x; h[1] = (f16_t)v.y;
        h[2] = (f16_t)v.z; h[3] = (f16_t)v.w;
        d4[c * 64 + lane] = h;
        float h0 = (float)h[0], h1 = (float)h[1];
        float h2 = (float)h[2], h3 = (float)h[3];
        s += h0 * h0 + h1 * h1 + h2 * h2 + h3 * h3;
    }
    #pragma unroll
    for (int off = 32; off > 0; off >>= 1) s += __shfl_down(s, off);
    if (lane == 0) nrm[r] = s;
}

// ---------------------------------------------------------------- main GEMM
__global__ __launch_bounds__(512, 2) void mmd_mfma(
    const f16_t* __restrict__ Xh, const f16_t* __restrict__ Yh,
    const float* __restrict__ nx, const float* __restrict__ ny,
    double* __restrict__ partials) {
    // A-tile | B-tile, each BM x BK fp16 = 16 KB (32 KB total). Row-major,
    // row stride BK (64 B), contiguous (required by global_load_lds
    // wave-uniform-base + lane*16 semantics).
    __shared__ __align__(16) f16_t lds[2 * TILE];
    __shared__ double wred[8];

    const int b = blockIdx.x;
    const f16_t *A, *B;
    const float *nA, *nB;
    int tr, tc;
    double coef;
    if (b < 2 * TRI) {
        int u = (b < TRI) ? b : b - TRI;
        int r = 0;
        while (u >= NT - r) { u -= NT - r; r++; }
        tr = r; tc = r + u;
        double w = (tr == tc) ? 1.0 : 2.0;   // off-diagonal tiles count twice
        if (b < TRI) { A = Xh; B = Xh; nA = nx; nB = nx;
                       coef = w / ((double)NROWS * (double)(NROWS - 1)); }
        else         { A = Yh; B = Yh; nA = ny; nB = ny;
                       coef = w / ((double)MROWS * (double)(MROWS - 1)); }
    } else {
        int u = b - 2 * TRI;
        tr = u / NT; tc = u % NT;
        A = Xh; B = Yh; nA = nx; nB = ny;
        coef = -2.0 / ((double)NROWS * (double)MROWS);
    }

    const int t    = threadIdx.x;
    const int wave = t >> 6;            // 0..7; waves 4x2: wm=wave>>1, wn=wave&1
    const int lane = t & 63;
    const int wm   = wave >> 1;         // 0..3 -> 64-row band
    const int wn   = wave & 1;          // 0..1 -> 128-col band

    // staging: 32 KB / (512 lanes x 16 B x 4 instr) ; wave w issues instrs
    // w*4..w*4+3 of 32. Per instr: 16 rows (4 lanes/row, 16 B/lane).
    const f16_t* Abase = A + (size_t)tr * BM * DDIM;
    const f16_t* Bbase = B + (size_t)tc * BM * DDIM;
    const int lrow = lane >> 2;         // 0..15 within row-group
    const int lcol = (lane & 3) * 8;    // f16 elems; *2B = 16 B chunks
    const f16_t* gsrc[4];
    int ldsoff[4];
    #pragma unroll
    for (int i = 0; i < 4; i++) {
        int idx = wave * 4 + i;         // 0..31
        int tile = idx >> 4;            // 0=A, 1=B
        int rg   = idx & 15;            // row-group of 16 rows
        const f16_t* base = tile ? Bbase : Abase;
        gsrc[i] = base + (size_t)(rg * 16 + lrow) * DDIM + lcol;
        ldsoff[i] = tile * TILE + (rg * 16 + lrow) * BK + lcol;
    }

    const int m    = lane & 15;         // row within 16x16 subtile
    const int quad = lane >> 4;         // k-chunk: k = quad*8 + j

    // hoist epilogue norm loads off the critical tail
    float na[16], nb[8];
    #pragma unroll
    for (int i = 0; i < 4; i++)
        #pragma unroll
        for (int r = 0; r < 4; r++)
            na[i * 4 + r] = nA[tr * BM + wm * 64 + i * 16 + quad * 4 + r];
    #pragma unroll
    for (int j = 0; j < 8; j++)
        nb[j] = nB[tc * BM + wn * 128 + j * 16 + m];

    floatx4 acc[4][8];
    #pragma unroll
    for (int i = 0; i < 4; i++)
        #pragma unroll
        for (int j = 0; j < 8; j++) acc[i][j] = (floatx4){0.f, 0.f, 0.f, 0.f};

    for (int k0 = 0; k0 < DDIM; k0 += BK) {
        __syncthreads();                 // previous compute done before overwrite
        #pragma unroll
        for (int i = 0; i < 4; i++) {
            __builtin_amdgcn_global_load_lds(
                (const __attribute__((address_space(1))) void*)(gsrc[i] + k0),
                (__attribute__((address_space(3))) void*)(lds + ldsoff[i]),
                16, 0, 0);
        }
        __syncthreads();                 // drains vmcnt before barrier

        f16x8 ah[4], bh[8];
        #pragma unroll
        for (int s = 0; s < 4; s++) {
            int arow = wm * 64 + s * 16 + m;
            ah[s] = *(const f16x8*)&lds[arow * BK + quad * 8];
        }
        #pragma unroll
        for (int u = 0; u < 8; u++) {
            int brow = wn * 128 + u * 16 + m;
            bh[u] = *(const f16x8*)&lds[TILE + brow * BK + quad * 8];
        }
        #pragma unroll
        for (int i = 0; i < 4; i++)
            #pragma unroll
            for (int j = 0; j < 8; j++)
                acc[i][j] = __builtin_amdgcn_mfma_f32_16x16x32_f16(ah[i], bh[j], acc[i][j], 0, 0, 0);
    }

    // epilogue: C/D layout col=lane&15 (B-row), row=quad*4+reg (A-row)
    const float inv_s2 = 1.0f / 2025.0f;
    float lsum = 0.f;
    #pragma unroll
    for (int i = 0; i < 4; i++)
        #pragma unroll
        for (int j = 0; j < 8; j++)
            #pragma unroll
            for (int r = 0; r < 4; r++) {
                float arg = (2.f * acc[i][j][r] - na[i * 4 + r] - nb[j]) * inv_s2;
                lsum += __expf(arg);
            }

    // in-wave fp64 reduce (no barriers), then 8-wave LDS combine; plain store
    double d = (double)lsum;
    #pragma unroll
    for (int off = 32; off > 0; off >>= 1) d += __shfl_down(d, off);
    if (lane == 0) wred[wave] = d;
    __syncthreads();
    if (t == 0) {
        double s = 0.0;
        #pragma unroll
        for (int w = 0; w < 8; w++) s += wred[w];
        partials[b] = s * coef;
    }
}

__global__ __launch_bounds__(256) void final_reduce(const double* __restrict__ partials,
                                                    float* __restrict__ out) {
    __shared__ double red[256];
    int t = threadIdx.x;
    double s = 0.0;
    for (int i = t; i < NBLK; i += 256) s += partials[i];
    red[t] = s;
    __syncthreads();
    for (int off = 128; off > 0; off >>= 1) {
        if (t < off) red[t] += red[t + off];
        __syncthreads();
    }
    if (t == 0) {
        // analytic diagonal subtraction: 1/(n-1) + 1/(m-1)
        double mmd = red[0] - 1.0 / (double)(NROWS - 1) - 1.0 / (double)(MROWS - 1);
        out[0] = (float)mmd;
    }
}

extern "C" void kernel_launch(void* const* d_in, const int* in_sizes, int n_in,
                              void* d_out, int out_size, void* d_ws, size_t ws_size,
                              hipStream_t stream) {
    const float* X = (const float*)d_in[0];   // inputs  [4096,1024] fp32
    const float* Y = (const float*)d_in[1];   // samples [4096,1024] fp32
    float* out = (float*)d_out;

    // workspace: partials | nx | ny | Xh | Yh  (~16.7 MB)
    char* p = (char*)d_ws;
    double* partials = (double*)p;            p += ((size_t)NBLK * sizeof(double) + 255) & ~255ULL;
    float* nx = (float*)p;                    p += (size_t)NROWS * sizeof(float);
    float* ny = (float*)p;                    p += (size_t)MROWS * sizeof(float);
    f16_t* Xh = (f16_t*)p;                    p += (size_t)NROWS * DDIM * sizeof(f16_t);
    f16_t* Yh = (f16_t*)p;

    convert_kernel<<<(NROWS + MROWS) / 4, 256, 0, stream>>>(X, Y, Xh, Yh, nx, ny);
    mmd_mfma<<<NBLK, 512, 0, stream>>>(Xh, Yh, nx, ny, partials);
    final_reduce<<<1, 256, 0, stream>>>(partials, out);
}

// Round 10
// 163.513 us; speedup vs baseline: 2.0650x; 1.1943x over previous
//
#include <hip/hip_runtime.h>
#include <math.h>

// MMD loss, single-pass fp16 MFMA. N=M=4096, D=1024, sigma^2=2025.
// x -> xh = fp16(x) (RNE); norms computed FROM THE ROUNDED vectors so the
// kernel evaluates the exact MMD of the perturbed sets {xh},{yh}. Per-block
// fp64 partials + tiny reduce kernel (NO fences in main kernel: round-4
// showed agent-scope fence = per-XCD L2 invalidate, 1.45x slowdown).
// Round 10: exact R5 structure (best measured: 98 us mmd) + XOR-swizzled
// LDS chunk layout ONLY (clean A/B; R7's swizzle test was confounded by
// BK=64/VGPR-108 occupancy loss). Slot c' of row r holds global chunk
// c'^f(r), f(r)=(r^(r>>2))&3. Store side free: glds lane->slot mapping is
// fixed by HW, so each lane FETCHES the chunk belonging in its slot (lane
// permutation within a row; same cache lines). Read side: ac=quad^f(m),
// hand-verified to spread 16 lanes/quad over 8 superbanks x 2 = free.

typedef _Float16 f16_t;
typedef _Float16 f16x4 __attribute__((ext_vector_type(4)));
typedef _Float16 f16x8 __attribute__((ext_vector_type(8)));
typedef float floatx4 __attribute__((ext_vector_type(4)));

#define NROWS 4096
#define MROWS 4096
#define DDIM  1024
#define BM    128
#define BK    32                      // fp16 elements per K-step (64 B/row)
#define TILE  (BM * BK)               // 4096 f16 per tile (8 KB)
#define NT    (NROWS / BM)            // 32 tiles per dim
#define TRI   (NT * (NT + 1) / 2)     // 528 triangular tiles
#define NBLK  (2 * TRI + NT * NT)     // 2080 blocks

// ---------------------------------------------------------------- convert
// Wave-per-row: 2048 blocks x 4 waves cover 8192 rows. Each lane loads
// 4 float4 (64 lanes x 16 B = 1 KB per instr, fully coalesced), converts to
// fp16, stores f16x4; norm of the ROUNDED row shuffle-reduced in-wave.
__global__ __launch_bounds__(256) void convert_kernel(
    const float* __restrict__ X, const float* __restrict__ Y,
    f16_t* __restrict__ Xh, f16_t* __restrict__ Yh,
    float* __restrict__ nx, float* __restrict__ ny) {
    const int wid  = threadIdx.x >> 6;
    const int lane = threadIdx.x & 63;
    const int row  = blockIdx.x * 4 + wid;        // 0..8191
    const float* src;
    f16_t* dst;
    float* nrm;
    int r;
    if (row < NROWS) {
        r = row;         src = X + (size_t)r * DDIM;
        dst = Xh + (size_t)r * DDIM;  nrm = nx;
    } else {
        r = row - NROWS; src = Y + (size_t)r * DDIM;
        dst = Yh + (size_t)r * DDIM;  nrm = ny;
    }
    const float4* s4 = (const float4*)src;        // 256 float4 per row
    f16x4* d4 = (f16x4*)dst;
    float s = 0.f;
    #pragma unroll
    for (int c = 0; c < 4; c++) {
        float4 v = s4[c * 64 + lane];
        f16x4 h;
        h[0] = (f16_t)v.x; h[1] = (f16_t)v.y;
        h[2] = (f16_t)v.z; h[3] = (f16_t)v.w;
        d4[c * 64 + lane] = h;
        float h0 = (float)h[0], h1 = (float)h[1];
        float h2 = (float)h[2], h3 = (float)h[3];
        s += h0 * h0 + h1 * h1 + h2 * h2 + h3 * h3;
    }
    #pragma unroll
    for (int off = 32; off > 0; off >>= 1) s += __shfl_down(s, off);
    if (lane == 0) nrm[r] = s;
}

// ---------------------------------------------------------------- main GEMM
__global__ __launch_bounds__(256) void mmd_mfma(
    const f16_t* __restrict__ Xh, const f16_t* __restrict__ Yh,
    const float* __restrict__ nx, const float* __restrict__ ny,
    double* __restrict__ partials) {
    // A-tile | B-tile, each BM x BK fp16 = 8 KB (16 KB total). Row stride
    // BK (64 B); slot chunk c' of row r holds global chunk c'^f(r).
    __shared__ __align__(16) f16_t lds[2 * TILE];
    __shared__ double wred[4];

    const int b = blockIdx.x;
    const f16_t *A, *B;
    const float *nA, *nB;
    int tr, tc;
    double coef;
    if (b < 2 * TRI) {
        int u = (b < TRI) ? b : b - TRI;
        int r = 0;
        while (u >= NT - r) { u -= NT - r; r++; }
        tr = r; tc = r + u;
        double w = (tr == tc) ? 1.0 : 2.0;   // off-diagonal tiles count twice
        if (b < TRI) { A = Xh; B = Xh; nA = nx; nB = nx;
                       coef = w / ((double)NROWS * (double)(NROWS - 1)); }
        else         { A = Yh; B = Yh; nA = ny; nB = ny;
                       coef = w / ((double)MROWS * (double)(MROWS - 1)); }
    } else {
        int u = b - 2 * TRI;
        tr = u / NT; tc = u % NT;
        A = Xh; B = Yh; nA = nx; nB = ny;
        coef = -2.0 / ((double)NROWS * (double)MROWS);
    }

    const int t    = threadIdx.x;
    const int wave = t >> 6;            // 0..3; waves 2x2: wm=wave>>1, wn=wave&1
    const int lane = t & 63;
    const int wm   = wave >> 1;
    const int wn   = wave & 1;

    // staging: 16 glds instrs (2 tiles x 8 row-groups of 16 rows); wave w
    // issues instrs w*4 .. w*4+3. Per instr: 64 lanes x 16 B = 16 rows.
    // Lane l -> LDS slot (row lrow, chunk l&3) fixed by HW; lane fetches
    // global chunk (l&3)^f(lrow) so slot c' holds chunk c'^f(row).
    const f16_t* Abase = A + (size_t)tr * BM * DDIM;
    const f16_t* Bbase = B + (size_t)tc * BM * DDIM;
    const int lrow = lane >> 2;         // 0..15 within row-group
    const int schunk = (lane & 3) ^ ((lrow ^ (lrow >> 2)) & 3);
    const f16_t* gsrc[4];
    int ldsoff[4];
    #pragma unroll
    for (int i = 0; i < 4; i++) {
        int idx = wave * 4 + i;         // 0..15
        int tile = idx >> 3;            // 0=A, 1=B
        int rg   = idx & 7;             // row-group
        const f16_t* base = tile ? Bbase : Abase;
        gsrc[i] = base + (size_t)(rg * 16 + lrow) * DDIM + schunk * 8;
        ldsoff[i] = tile * TILE + rg * 16 * BK;   // wave-uniform base
    }

    const int m    = lane & 15;         // row within 16x16 subtile
    const int quad = lane >> 4;         // k-chunk: k = quad*8 + j
    const int ac   = quad ^ ((m ^ (m >> 2)) & 3);  // swizzled read chunk

    // hoist epilogue norm loads off the critical tail
    float na[16], nb[4];
    #pragma unroll
    for (int i = 0; i < 4; i++) {
        #pragma unroll
        for (int r = 0; r < 4; r++)
            na[i * 4 + r] = nA[tr * BM + wm * 64 + i * 16 + quad * 4 + r];
        nb[i] = nB[tc * BM + wn * 64 + i * 16 + m];
    }

    floatx4 acc_r[4][4];
    #pragma unroll
    for (int i = 0; i < 4; i++)
        #pragma unroll
        for (int j = 0; j < 4; j++) acc_r[i][j] = (floatx4){0.f, 0.f, 0.f, 0.f};

    for (int k0 = 0; k0 < DDIM; k0 += BK) {
        __syncthreads();                 // previous compute done before overwrite
        #pragma unroll
        for (int i = 0; i < 4; i++) {
            __builtin_amdgcn_global_load_lds(
                (const __attribute__((address_space(1))) void*)(gsrc[i] + k0),
                (__attribute__((address_space(3))) void*)(lds + ldsoff[i]),
                16, 0, 0);
        }
        __syncthreads();                 // drains vmcnt before barrier

        f16x8 ah[4], bh[4];
        #pragma unroll
        for (int s = 0; s < 4; s++) {
            int arow = wm * 64 + s * 16 + m;
            int brow = wn * 64 + s * 16 + m;
            ah[s] = *(const f16x8*)&lds[arow * BK + ac * 8];
            bh[s] = *(const f16x8*)&lds[TILE + brow * BK + ac * 8];
        }
        #pragma unroll
        for (int i = 0; i < 4; i++)
            #pragma unroll
            for (int j = 0; j < 4; j++)
                acc_r[i][j] = __builtin_amdgcn_mfma_f32_16x16x32_f16(ah[i], bh[j], acc_r[i][j], 0, 0, 0);
    }

    // epilogue: C/D layout col=lane&15 (B-row), row=quad*4+reg (A-row)
    const float inv_s2 = 1.0f / 2025.0f;
    float lsum = 0.f;
    #pragma unroll
    for (int i = 0; i < 4; i++)
        #pragma unroll
        for (int j = 0; j < 4; j++)
            #pragma unroll
            for (int r = 0; r < 4; r++) {
                float arg = (2.f * acc_r[i][j][r] - na[i * 4 + r] - nb[j]) * inv_s2;
                lsum += __expf(arg);
            }

    // in-wave fp64 reduce (no barriers), then 4-wave LDS combine; plain store
    double d = (double)lsum;
    #pragma unroll
    for (int off = 32; off > 0; off >>= 1) d += __shfl_down(d, off);
    if (lane == 0) wred[wave] = d;
    __syncthreads();
    if (t == 0)
        partials[b] = (wred[0] + wred[1] + wred[2] + wred[3]) * coef;
}

__global__ __launch_bounds__(256) void final_reduce(const double* __restrict__ partials,
                                                    float* __restrict__ out) {
    __shared__ double red[256];
    int t = threadIdx.x;
    double s = 0.0;
    for (int i = t; i < NBLK; i += 256) s += partials[i];
    red[t] = s;
    __syncthreads();
    for (int off = 128; off > 0; off >>= 1) {
        if (t < off) red[t] += red[t + off];
        __syncthreads();
    }
    if (t == 0) {
        // analytic diagonal subtraction: 1/(n-1) + 1/(m-1)
        double mmd = red[0] - 1.0 / (double)(NROWS - 1) - 1.0 / (double)(MROWS - 1);
        out[0] = (float)mmd;
    }
}

extern "C" void kernel_launch(void* const* d_in, const int* in_sizes, int n_in,
                              void* d_out, int out_size, void* d_ws, size_t ws_size,
                              hipStream_t stream) {
    const float* X = (const float*)d_in[0];   // inputs  [4096,1024] fp32
    const float* Y = (const float*)d_in[1];   // samples [4096,1024] fp32
    float* out = (float*)d_out;

    // workspace: partials | nx | ny | Xh | Yh  (~16.7 MB)
    char* p = (char*)d_ws;
    double* partials = (double*)p;            p += ((size_t)NBLK * sizeof(double) + 255) & ~255ULL;
    float* nx = (float*)p;                    p += (size_t)NROWS * sizeof(float);
    float* ny = (float*)p;                    p += (size_t)MROWS * sizeof(float);
    f16_t* Xh = (f16_t*)p;                    p += (size_t)NROWS * DDIM * sizeof(f16_t);
    f16_t* Yh = (f16_t*)p;

    convert_kernel<<<(NROWS + MROWS) / 4, 256, 0, stream>>>(X, Y, Xh, Yh, nx, ny);
    mmd_mfma<<<NBLK, 256, 0, stream>>>(Xh, Yh, nx, ny, partials);
    final_reduce<<<1, 256, 0, stream>>>(partials, out);
}